// Round 7
// baseline (84.425 us; speedup 1.0000x reference)
//
#include <hip/hip_runtime.h>

// HopfRNNCellTheta: T=64 < UNITS=1024 -> z[:,0] stays 0 -> A unused,
// y_t = 0.5*(B@x_t). Output = REAL part only, float32[64][1024][1024].
// out[t][n][u] = ReY[s][n], s = t+u-1023, if s>=0 else 0.
//
// Round-6 lesson: fusing gemv with the 256MB zero-fill starves the gemv's
// prefetch loads behind the store flood (store-queue contention), stretching
// a ~9us gemv to ~60us. So: K1 = gemv alone -> stash (d_ws, 256KB);
// K2 = single writer covering EVERY output word once (zero prefix + band
// tail per row, coalesced float4 stores, stash read from L2).

#define NDIM 1024

// ---- K1: ReY[t][n] -> stash[n*64+t]. 256 blocks x 4 waves; wave=row n,
// lane=t. B chunk in LDS (wave-uniform float4 reads), x transposed in LDS
// (conflict-free), register double-buffer prefetch. ----
__global__ __launch_bounds__(256) void gemv_stash(
    const float* __restrict__ x_re, const float* __restrict__ x_im,
    const float* __restrict__ B_re, const float* __restrict__ B_im,
    float* __restrict__ stash) {
  __shared__ float xs1[64][65];   // xs1[m][t]
  __shared__ float xs2[64][65];
  __shared__ float bs1[4][68];
  __shared__ float bs2[4][68];
  const int tid = threadIdx.x;
  const int t = tid & 63;
  const int ng = tid >> 6;
  const int n = blockIdx.x * 4 + ng;
  const int tr = (tid >> 4);
  const int j0 = (tid & 15) * 4;

  float4 r1[4], r2[4];
  float bb1, bb2;
  float a1 = 0.f, a2 = 0.f;

#pragma unroll
  for (int k = 0; k < 4; ++k) {
    r1[k] = *(const float4*)(x_re + (k * 16 + tr) * NDIM + j0);
    r2[k] = *(const float4*)(x_im + (k * 16 + tr) * NDIM + j0);
  }
  bb1 = B_re[n * NDIM + t];
  bb2 = B_im[n * NDIM + t];

  for (int c = 0; c < 16; ++c) {
#pragma unroll
    for (int k = 0; k < 4; ++k) {
      const int row = k * 16 + tr;
      xs1[j0 + 0][row] = r1[k].x;
      xs1[j0 + 1][row] = r1[k].y;
      xs1[j0 + 2][row] = r1[k].z;
      xs1[j0 + 3][row] = r1[k].w;
      xs2[j0 + 0][row] = r2[k].x;
      xs2[j0 + 1][row] = r2[k].y;
      xs2[j0 + 2][row] = r2[k].z;
      xs2[j0 + 3][row] = r2[k].w;
    }
    bs1[ng][t] = bb1;
    bs2[ng][t] = bb2;
    __syncthreads();

    if (c < 15) {
      const int m0 = (c + 1) * 64;
#pragma unroll
      for (int k = 0; k < 4; ++k) {
        r1[k] = *(const float4*)(x_re + (k * 16 + tr) * NDIM + m0 + j0);
        r2[k] = *(const float4*)(x_im + (k * 16 + tr) * NDIM + m0 + j0);
      }
      bb1 = B_re[n * NDIM + m0 + t];
      bb2 = B_im[n * NDIM + m0 + t];
    }

#pragma unroll
    for (int m4 = 0; m4 < 16; ++m4) {
      const float4 b1 = *(const float4*)&bs1[ng][m4 * 4];
      const float4 b2 = *(const float4*)&bs2[ng][m4 * 4];
      const int mm = m4 * 4;
      a1 = fmaf(b1.x, xs1[mm + 0][t], a1);
      a2 = fmaf(b2.x, xs2[mm + 0][t], a2);
      a1 = fmaf(b1.y, xs1[mm + 1][t], a1);
      a2 = fmaf(b2.y, xs2[mm + 1][t], a2);
      a1 = fmaf(b1.z, xs1[mm + 2][t], a1);
      a2 = fmaf(b2.z, xs2[mm + 2][t], a2);
      a1 = fmaf(b1.w, xs1[mm + 3][t], a1);
      a2 = fmaf(b2.w, xs2[mm + 3][t], a2);
    }
    __syncthreads();
  }
  stash[(n << 6) + t] = 0.5f * (a1 - a2);
}

// ---- K2: write all 256MB once. Block b: plane t = b&63, row group g = b>>6
// (rows n in [g*64, g*64+64)). Per float4 word: components j -> s = sb+j,
// value = s>=0 ? stash[n*64+s] : 0. Coalesced 16B stores; ~97% of words take
// the pure-zero fast path. ----
__global__ __launch_bounds__(256) void fill_band(
    const float* __restrict__ stash, float* __restrict__ out) {
  const int b = blockIdx.x;
  const int t = b & 63;
  const int g = b >> 6;
  float4* o4 = (float4*)out + ((long long)t << 18) + (g << 14);
  const float4 z = make_float4(0.f, 0.f, 0.f, 0.f);
  for (int w = threadIdx.x; w < 64 * 256; w += 256) {
    const int row = w >> 8;
    const int u4 = w & 255;
    const int sb = t + 4 * u4 - 1023;       // s of component 0; sb+3 <= t
    float4 v = z;
    if (sb >= 0) {                           // fully in band
      const float* sp = stash + (((g << 6) + row) << 6) + sb;
      v = make_float4(sp[0], sp[1], sp[2], sp[3]);
    } else if (sb > -4) {                    // boundary word
      const float* sp = stash + (((g << 6) + row) << 6);
      if (sb + 1 >= 0) v.y = sp[sb + 1];
      if (sb + 2 >= 0) v.z = sp[sb + 2];
      v.w = sp[sb + 3];                      // sb+3 >= 0 here
    }
    o4[w] = v;
  }
}

// ---- fallback (round-6 fused, known-passing; used only if ws too small) ----
__global__ __launch_bounds__(256) void hopf_fused_fb(
    const float* __restrict__ x_re, const float* __restrict__ x_im,
    const float* __restrict__ B_re, const float* __restrict__ B_im,
    float* __restrict__ out) {
  __shared__ float s1[64][65];
  __shared__ float s2[64][65];
  const int tid = threadIdx.x;
  if (blockIdx.x >= 256) {
    float4* out4 = (float4*)out;
    const float4 z = make_float4(0.f, 0.f, 0.f, 0.f);
    const int stride = 768 * 256;
    for (int q = (int)(blockIdx.x - 256) * 256 + tid; q < (1 << 24);
         q += stride) {
      const int t = q >> 18;
      const int u4 = q & 255;
      const int sb = t + 4 * u4 - 1023;
      if (sb <= -4) {
        out4[q] = z;
      } else if (sb < 0) {
        float* p = out + ((long long)q << 2);
        p[0] = 0.f;
        if (sb + 1 < 0) p[1] = 0.f;
        if (sb + 2 < 0) p[2] = 0.f;
      }
    }
    return;
  }
  const int t = tid & 63;
  const int ng = tid >> 6;
  const int n = blockIdx.x * 4 + ng;
  const float* p1 = B_re + n * NDIM;
  const float* p2 = B_im + n * NDIM;
  float a1 = 0.f, a2 = 0.f;
  for (int m0 = 0; m0 < NDIM; m0 += 64) {
    __syncthreads();
#pragma unroll
    for (int k = 0; k < 16; ++k) {
      const int s = tid + k * 256;
      const int tr2 = s >> 6, j = s & 63;
      s1[tr2][j] = x_re[tr2 * NDIM + m0 + j];
      s2[tr2][j] = x_im[tr2 * NDIM + m0 + j];
    }
    __syncthreads();
#pragma unroll 16
    for (int mm = 0; mm < 64; ++mm) {
      a1 = fmaf(p1[m0 + mm], s1[t][mm], a1);
      a2 = fmaf(p2[m0 + mm], s2[t][mm], a2);
    }
  }
  const float yv = 0.5f * (a1 - a2);
  const long long rowoff = (long long)(n << 10);
  for (int tt = t; tt < 64; ++tt) {
    out[((long long)tt << 20) + rowoff + (1023 - tt) + t] = yv;
  }
}

extern "C" void kernel_launch(void* const* d_in, const int* in_sizes, int n_in,
                              void* d_out, int out_size, void* d_ws, size_t ws_size,
                              hipStream_t stream) {
  (void)in_sizes; (void)n_in; (void)out_size;
  const float* x_re = (const float*)d_in[0];
  const float* x_im = (const float*)d_in[1];
  const float* B_re = (const float*)d_in[4];
  const float* B_im = (const float*)d_in[5];
  float* out = (float*)d_out;

  if (ws_size >= (size_t)(1024 * 64 * sizeof(float))) {
    float* stash = (float*)d_ws;
    gemv_stash<<<256, 256, 0, stream>>>(x_re, x_im, B_re, B_im, stash);
    fill_band<<<1024, 256, 0, stream>>>(stash, out);
  } else {
    hopf_fused_fb<<<1024, 256, 0, stream>>>(x_re, x_im, B_re, B_im, out);
  }
}